// Round 1
// baseline (609.602 us; speedup 1.0000x reference)
//
#include <hip/hip_runtime.h>

#define DIM 2048
#define NB 8

typedef _Float16 f16;
typedef __attribute__((ext_vector_type(8))) _Float16 f16x8;
typedef __attribute__((ext_vector_type(4))) _Float16 f16x4;
typedef __attribute__((ext_vector_type(4))) float f32x4;
typedef __attribute__((ext_vector_type(4))) unsigned u32x4;

// ---- float <-> orderable uint key (for atomicMax on floats) ----
__device__ __forceinline__ unsigned fkey(float f) {
    unsigned u = __float_as_uint(f);
    return (u & 0x80000000u) ? ~u : (u | 0x80000000u);
}
__device__ __forceinline__ float fdecode(unsigned k) {
    return (k & 0x80000000u) ? __uint_as_float(k ^ 0x80000000u)
                             : __uint_as_float(~k);
}

// ---- fp32 -> fp16 conversion, float4 vectorized ----
__global__ __launch_bounds__(256) void k_convert(const float* __restrict__ src,
                                                 f16* __restrict__ dst, int n4) {
    int i = blockIdx.x * 256 + threadIdx.x;
    if (i >= n4) return;
    f32x4 v = ((const f32x4*)src)[i];
    ((f16x4*)dst)[i] = __builtin_convertvector(v, f16x4);
}

// ---- column sums of x over token axis (for v = mean) ----
__global__ __launch_bounds__(256) void k_colsum(const float* __restrict__ x,
                                                float* __restrict__ vsum) {
    int b = blockIdx.z;
    int c = blockIdx.x * 256 + threadIdx.x;
    int n0 = blockIdx.y * (DIM / 8);
    const float* p = x + ((size_t)b * DIM + n0) * DIM + c;
    float s = 0.f;
    #pragma unroll 8
    for (int n = 0; n < DIM / 8; ++n) s += p[(size_t)n * DIM];
    atomicAdd(&vsum[b * DIM + c], s);
}

// ---- 128x128 tile core: C = A @ Bt^T, both row-major stride DIM, f16 ----
// MFMA 16x16x32_f16 layouts (per guide §3, HW-verified):
//   A frag: A[m = lane&15][k = (lane>>4)*8 + e]
//   B frag: B[k = (lane>>4)*8 + e][n = lane&15]  (= Bt[n][k])
//   D:      D[row = (lane>>4)*4 + reg][col = lane&15]
__device__ __forceinline__ void gemm128_core(const f16* __restrict__ A,
                                             const f16* __restrict__ Bt,
                                             int br, int bc,
                                             f16 (*As)[72], f16 (*Bs)[72],
                                             f32x4 acc[4][4]) {
    const int tid  = threadIdx.x;
    const int lane = tid & 63;
    const int wave = tid >> 6;
    const int wr   = (wave >> 1) * 64;
    const int wc   = (wave & 1) * 64;
    const int l15  = lane & 15;
    const int quad = lane >> 4;

    #pragma unroll
    for (int i = 0; i < 4; ++i)
        #pragma unroll
        for (int j = 0; j < 4; ++j)
            acc[i][j] = (f32x4){0.f, 0.f, 0.f, 0.f};

    for (int kt = 0; kt < DIM / 64; ++kt) {
        __syncthreads();
        #pragma unroll
        for (int u = 0; u < 4; ++u) {
            int c   = tid + 256 * u;      // 0..1023 chunks of 8 f16
            int row = c >> 3;
            int seg = c & 7;
            f16x8 va = *(const f16x8*)(A  + (size_t)(br * 128 + row) * DIM + kt * 64 + seg * 8);
            *(f16x8*)(&As[row][seg * 8]) = va;
            f16x8 vb = *(const f16x8*)(Bt + (size_t)(bc * 128 + row) * DIM + kt * 64 + seg * 8);
            *(f16x8*)(&Bs[row][seg * 8]) = vb;
        }
        __syncthreads();
        #pragma unroll
        for (int kk = 0; kk < 2; ++kk) {
            f16x8 af[4], bf[4];
            #pragma unroll
            for (int i = 0; i < 4; ++i)
                af[i] = *(const f16x8*)(&As[wr + i * 16 + l15][kk * 32 + quad * 8]);
            #pragma unroll
            for (int j = 0; j < 4; ++j)
                bf[j] = *(const f16x8*)(&Bs[wc + j * 16 + l15][kk * 32 + quad * 8]);
            #pragma unroll
            for (int i = 0; i < 4; ++i)
                #pragma unroll
                for (int j = 0; j < 4; ++j)
                    acc[i][j] = __builtin_amdgcn_mfma_f32_16x16x32_f16(af[i], bf[j], acc[i][j], 0, 0, 0);
        }
    }
}

// ---- Gram: G_b = X_b @ X_b^T (symmetric; triangular block grid + mirror) ----
__global__ __launch_bounds__(256) void k_gram(const f16* __restrict__ Xall,
                                              f16* __restrict__ Gall,
                                              unsigned long xStride,
                                              unsigned long gStride) {
    const int b = blockIdx.y;
    const f16* X = Xall + (size_t)b * xStride;
    f16* G = Gall + (size_t)b * gStride;

    int t = blockIdx.x;
    int br = (int)((sqrtf(8.f * t + 1.f) - 1.f) * 0.5f);
    while ((br + 1) * (br + 2) / 2 <= t) ++br;
    while (br * (br + 1) / 2 > t) --br;
    int bc = t - br * (br + 1) / 2;   // bc <= br

    __shared__ __align__(16) f16 As[128][72];
    __shared__ __align__(16) f16 Bs[128][72];
    f32x4 acc[4][4];
    gemm128_core(X, X, br, bc, As, Bs, acc);

    const int lane = threadIdx.x & 63;
    const int wave = threadIdx.x >> 6;
    const int wr = (wave >> 1) * 64, wc = (wave & 1) * 64;
    const int l15 = lane & 15, quad = lane >> 4;
    #pragma unroll
    for (int i = 0; i < 4; ++i)
        #pragma unroll
        for (int j = 0; j < 4; ++j)
            #pragma unroll
            for (int r = 0; r < 4; ++r) {
                int row = br * 128 + wr + i * 16 + quad * 4 + r;
                int col = bc * 128 + wc + j * 16 + l15;
                f16 v = (f16)acc[i][j][r];
                G[(size_t)row * DIM + col] = v;
                if (br != bc) G[(size_t)col * DIM + row] = v;
            }
}

// ---- attn tile = scale * Wq @ G_b (G symmetric: rows of G serve as Bt rows),
//      fused row-max via shfl + atomicMax on uint keys ----
__global__ __launch_bounds__(256) void k_attn(const f16* __restrict__ Wq,
                                              const f16* __restrict__ Gall,
                                              unsigned* __restrict__ mkey,
                                              unsigned long gStride, int batchBase) {
    const int bz = blockIdx.z;
    const int bi = bz + batchBase;            // logical batch for mkey
    const f16* G = Gall + (size_t)bz * gStride;
    const int br = blockIdx.y, bc = blockIdx.x;

    __shared__ __align__(16) f16 As[128][72];
    __shared__ __align__(16) f16 Bs[128][72];
    f32x4 acc[4][4];
    gemm128_core(Wq, G, br, bc, As, Bs, acc);

    const int lane = threadIdx.x & 63;
    const int wave = threadIdx.x >> 6;
    const int wr = (wave >> 1) * 64;
    const int l15 = lane & 15, quad = lane >> 4;
    const float scale = 0.0625f;              // (2048/8)^-0.5

    #pragma unroll
    for (int i = 0; i < 4; ++i) {
        #pragma unroll
        for (int r = 0; r < 4; ++r) {
            float v = acc[i][0][r];
            v = fmaxf(v, acc[i][1][r]);
            v = fmaxf(v, acc[i][2][r]);
            v = fmaxf(v, acc[i][3][r]);
            #pragma unroll
            for (int m = 1; m <= 8; m <<= 1)
                v = fmaxf(v, __shfl_xor(v, m, 64));
            if (l15 == 0) {
                int row = br * 128 + wr + i * 16 + quad * 4 + r;
                atomicMax(&mkey[(size_t)bi * DIM + row], fkey(scale * v));
            }
        }
    }
}

// ---- out[b,i,j] = (vsum[b,i]/2048) * m[b,j] ----
__global__ __launch_bounds__(256) void k_final(const float* __restrict__ vsum,
                                               const unsigned* __restrict__ mkey,
                                               float* __restrict__ out) {
    int gid = blockIdx.x * 256 + threadIdx.x;     // 8*2048*512 total
    int b   = gid >> 20;
    int rem = gid & 1048575;
    int i   = rem >> 9;
    int jq  = rem & 511;
    float v = vsum[(b << 11) + i] * (1.f / 2048.f);
    u32x4 k = ((const u32x4*)mkey)[(b << 9) + jq];
    f32x4 o;
    o.x = v * fdecode(k.x);
    o.y = v * fdecode(k.y);
    o.z = v * fdecode(k.z);
    o.w = v * fdecode(k.w);
    ((f32x4*)out)[gid] = o;
}

extern "C" void kernel_launch(void* const* d_in, const int* in_sizes, int n_in,
                              void* d_out, int out_size, void* d_ws, size_t ws_size,
                              hipStream_t stream) {
    const float* x  = (const float*)d_in[0];
    const float* Wq = (const float*)d_in[1];
    float* out = (float*)d_out;
    char* ws = (char*)d_ws;

    const size_t elems = (size_t)DIM * DIM;       // 4,194,304
    unsigned* mkey = (unsigned*)ws;                         // 64 KB
    float*    vsum = (float*)(ws + 65536);                  // 64 KB
    f16*      Wqf  = (f16*)(ws + 131072);                   // 8 MB
    f16*      Xf   = (f16*)(ws + 131072 + elems * 2);

    const size_t need1 = 131072 + elems * 2 * (1 + NB + NB);  // ~142.7 MB
    const size_t need2 = 131072 + elems * 2 * (1 + NB + 1);   // ~84.0 MB

    hipMemsetAsync(ws, 0, 131072, stream);
    k_convert<<<4096, 256, 0, stream>>>(Wq, Wqf, (int)(elems / 4));
    k_colsum<<<dim3(8, 8, 8), 256, 0, stream>>>(x, vsum);

    if (ws_size >= need1) {
        f16* G = Xf + NB * elems;
        k_convert<<<32768, 256, 0, stream>>>(x, Xf, (int)(NB * elems / 4));
        k_gram<<<dim3(136, NB), 256, 0, stream>>>(Xf, G, elems, elems);
        k_attn<<<dim3(16, 16, NB), 256, 0, stream>>>(Wqf, G, mkey, elems, 0);
    } else if (ws_size >= need2) {
        f16* G = Xf + NB * elems;
        k_convert<<<32768, 256, 0, stream>>>(x, Xf, (int)(NB * elems / 4));
        for (int b = 0; b < NB; ++b) {
            k_gram<<<dim3(136, 1), 256, 0, stream>>>(Xf + (size_t)b * elems, G, 0, 0);
            k_attn<<<dim3(16, 16, 1), 256, 0, stream>>>(Wqf, G, mkey, 0, b);
        }
    } else {
        f16* G = Xf + elems;
        for (int b = 0; b < NB; ++b) {
            k_convert<<<4096, 256, 0, stream>>>(x + (size_t)b * elems, Xf, (int)(elems / 4));
            k_gram<<<dim3(136, 1), 256, 0, stream>>>(Xf, G, 0, 0);
            k_attn<<<dim3(16, 16, 1), 256, 0, stream>>>(Wqf, G, mkey, 0, b);
        }
    }
    k_final<<<32768, 256, 0, stream>>>(vsum, mkey, out);
}

// Round 2
// 524.410 us; speedup vs baseline: 1.1625x; 1.1625x over previous
//
#include <hip/hip_runtime.h>

#define DIM 2048
#define NB 8

typedef _Float16 f16;
typedef __attribute__((ext_vector_type(8))) _Float16 f16x8;
typedef __attribute__((ext_vector_type(4))) _Float16 f16x4;
typedef __attribute__((ext_vector_type(2))) _Float16 f16x2;
typedef __attribute__((ext_vector_type(4))) float f32x4;
typedef __attribute__((ext_vector_type(4))) unsigned u32x4;

// ---- float <-> orderable uint key (for atomicMax on floats) ----
__device__ __forceinline__ unsigned fkey(float f) {
    unsigned u = __float_as_uint(f);
    return (u & 0x80000000u) ? ~u : (u | 0x80000000u);
}
__device__ __forceinline__ float fdecode(unsigned k) {
    return (k & 0x80000000u) ? __uint_as_float(k ^ 0x80000000u)
                             : __uint_as_float(~k);
}

// ---- async global->LDS 16B DMA (dest = wave-uniform base + lane*16) ----
__device__ __forceinline__ void gld_lds16(const f16* g, f16* l) {
    __builtin_amdgcn_global_load_lds(
        (const __attribute__((address_space(1))) unsigned*)g,
        (__attribute__((address_space(3))) unsigned*)l, 16, 0, 0);
}

// ---- fp32 -> fp16 conversion, float4 vectorized ----
__global__ __launch_bounds__(256) void k_convert(const float* __restrict__ src,
                                                 f16* __restrict__ dst, int n4) {
    int i = blockIdx.x * 256 + threadIdx.x;
    if (i >= n4) return;
    f32x4 v = ((const f32x4*)src)[i];
    ((f16x4*)dst)[i] = __builtin_convertvector(v, f16x4);
}

// ---- fused: fp32->fp16 convert of x AND column sums over token axis ----
// grid (2, 32, NB), 256 thr. Each thread: 4 consecutive cols, 64 rows.
__global__ __launch_bounds__(256) void k_prep(const float* __restrict__ x,
                                              f16* __restrict__ Xf,
                                              float* __restrict__ vsum) {
    const int b  = blockIdx.z;
    const int c0 = blockIdx.x * 1024 + threadIdx.x * 4;
    const int n0 = blockIdx.y * 64;
    const float* px = x  + ((size_t)b * DIM + n0) * DIM + c0;
    f16*         pd = Xf + ((size_t)b * DIM + n0) * DIM + c0;
    f32x4 s = (f32x4){0.f, 0.f, 0.f, 0.f};
    #pragma unroll 8
    for (int n = 0; n < 64; ++n) {
        f32x4 v = *(const f32x4*)(px + (size_t)n * DIM);
        *(f16x4*)(pd + (size_t)n * DIM) = __builtin_convertvector(v, f16x4);
        s += v;
    }
    atomicAdd(&vsum[b * DIM + c0 + 0], s.x);
    atomicAdd(&vsum[b * DIM + c0 + 1], s.y);
    atomicAdd(&vsum[b * DIM + c0 + 2], s.z);
    atomicAdd(&vsum[b * DIM + c0 + 3], s.w);
}

// ---- column sums of x over token axis (fallback paths only) ----
__global__ __launch_bounds__(256) void k_colsum(const float* __restrict__ x,
                                                float* __restrict__ vsum) {
    int b = blockIdx.z;
    int c = blockIdx.x * 256 + threadIdx.x;
    int n0 = blockIdx.y * (DIM / 8);
    const float* p = x + ((size_t)b * DIM + n0) * DIM + c;
    float s = 0.f;
    #pragma unroll 8
    for (int n = 0; n < DIM / 8; ++n) s += p[(size_t)n * DIM];
    atomicAdd(&vsum[b * DIM + c], s);
}

// ---- 128x128 tile core: C = A @ Bt^T, both row-major stride DIM, f16 ----
// Staging: global_load_lds 16B, unpadded LDS 128 rows x 64 f16 per tile,
// XOR chunk swizzle: LDS row r slot s holds global chunk s ^ (r&7).
// MFMA 16x16x32_f16 layouts (HW-verified):
//   A frag: A[m = lane&15][k = (lane>>4)*8 + e]
//   B frag: Bt[n = lane&15][k = (lane>>4)*8 + e]
//   D:      D[row = (lane>>4)*4 + reg][col = lane&15]
__device__ __forceinline__ void gemm128_core(const f16* __restrict__ A,
                                             const f16* __restrict__ Bt,
                                             int br, int bc,
                                             f16* As, f16* Bs,
                                             f32x4 acc[4][4]) {
    const int tid  = threadIdx.x;
    const int ln   = tid & 63;
    const int wv   = tid >> 6;
    const int l15  = ln & 15;
    const int quad = ln >> 4;
    const int wr   = (wv >> 1) * 64;
    const int wc   = (wv & 1) * 64;
    const int lrow = ln >> 3;            // 0..7 : row within 8-row chunk
    const int lg   = (ln & 7) ^ lrow;    // swizzled source 16B-chunk index
    const int swz  = l15 & 7;

    const f16* gA = A  + (size_t)(br * 128 + wv * 32 + lrow) * DIM + lg * 8;
    const f16* gB = Bt + (size_t)(bc * 128 + wv * 32 + lrow) * DIM + lg * 8;
    f16* lA = As + wv * 2048 + ln * 8;
    f16* lB = Bs + wv * 2048 + ln * 8;

    #pragma unroll
    for (int i = 0; i < 4; ++i)
        #pragma unroll
        for (int j = 0; j < 4; ++j)
            acc[i][j] = (f32x4){0.f, 0.f, 0.f, 0.f};

    for (int kt = 0; kt < DIM / 64; ++kt) {
        __syncthreads();
        #pragma unroll
        for (int u = 0; u < 4; ++u) {
            gld_lds16(gA + (size_t)u * 8 * DIM, lA + u * 512);
            gld_lds16(gB + (size_t)u * 8 * DIM, lB + u * 512);
        }
        gA += 64; gB += 64;
        __syncthreads();
        #pragma unroll
        for (int kk = 0; kk < 2; ++kk) {
            const int s = (kk * 4 + quad) ^ swz;
            f16x8 af[4], bf[4];
            #pragma unroll
            for (int i = 0; i < 4; ++i)
                af[i] = *(const f16x8*)(As + (wr + i * 16 + l15) * 64 + s * 8);
            #pragma unroll
            for (int j = 0; j < 4; ++j)
                bf[j] = *(const f16x8*)(Bs + (wc + j * 16 + l15) * 64 + s * 8);
            #pragma unroll
            for (int i = 0; i < 4; ++i)
                #pragma unroll
                for (int j = 0; j < 4; ++j)
                    acc[i][j] = __builtin_amdgcn_mfma_f32_16x16x32_f16(af[i], bf[j], acc[i][j], 0, 0, 0);
        }
    }
}

// ---- Gram: G_b = X_b @ X_b^T (symmetric; triangular grid, LDS-transposed mirror) ----
__global__ __launch_bounds__(256) void k_gram(const f16* __restrict__ Xall,
                                              f16* __restrict__ Gall,
                                              unsigned long xStride,
                                              unsigned long gStride) {
    const int b = blockIdx.y;
    const f16* X = Xall + (size_t)b * xStride;
    f16* G = Gall + (size_t)b * gStride;

    int t = blockIdx.x;
    int br = (int)((sqrtf(8.f * t + 1.f) - 1.f) * 0.5f);
    while ((br + 1) * (br + 2) / 2 <= t) ++br;
    while (br * (br + 1) / 2 > t) --br;
    int bc = t - br * (br + 1) / 2;   // bc <= br

    __shared__ __align__(16) f16 smem[128 * 136];   // 34.8 KB: As+Bs, reused as T
    f16* As = smem;
    f16* Bs = smem + 8192;
    f32x4 acc[4][4];
    gemm128_core(X, X, br, bc, As, Bs, acc);

    const int tid = threadIdx.x;
    const int ln = tid & 63;
    const int wv = tid >> 6;
    const int wr = (wv >> 1) * 64, wc = (wv & 1) * 64;
    const int l15 = ln & 15, quad = ln >> 4;

    // own tile: direct stores (lanes of a quad write 32B-contiguous runs)
    #pragma unroll
    for (int i = 0; i < 4; ++i)
        #pragma unroll
        for (int j = 0; j < 4; ++j)
            #pragma unroll
            for (int r = 0; r < 4; ++r) {
                int row = br * 128 + wr + i * 16 + quad * 4 + r;
                int col = bc * 128 + wc + j * 16 + l15;
                G[(size_t)row * DIM + col] = (f16)acc[i][j][r];
            }

    if (br != bc) {
        // mirror tile via LDS transpose -> coalesced 16B stores
        __syncthreads();
        f16* T = smem;   // 128 rows x 136 f16 (pad keeps 16B alignment, kills conflicts)
        #pragma unroll
        for (int i = 0; i < 4; ++i)
            #pragma unroll
            for (int j = 0; j < 4; ++j)
                #pragma unroll
                for (int h = 0; h < 2; ++h) {
                    int row = wr + i * 16 + quad * 4 + h * 2;
                    int col = wc + j * 16 + l15;
                    f16x2 v = {(f16)acc[i][j][h * 2], (f16)acc[i][j][h * 2 + 1]};
                    *(f16x2*)(T + col * 136 + row) = v;
                }
        __syncthreads();
        #pragma unroll
        for (int p = 0; p < 8; ++p) {
            int ch = p * 256 + tid;          // 0..2047
            int rt = ch >> 4, seg = ch & 15;
            f16x8 v = *(const f16x8*)(T + rt * 136 + seg * 8);
            *(f16x8*)(G + (size_t)(bc * 128 + rt) * DIM + br * 128 + seg * 8) = v;
        }
    }
}

// ---- attn tile = scale * Wq @ G_b (G symmetric: rows serve as Bt rows),
//      fused row-max via shfl + atomicMax on uint keys ----
__global__ __launch_bounds__(256) void k_attn(const f16* __restrict__ Wq,
                                              const f16* __restrict__ Gall,
                                              unsigned* __restrict__ mkey,
                                              unsigned long gStride, int batchBase) {
    const int bz = blockIdx.z;
    const int bi = bz + batchBase;
    const f16* G = Gall + (size_t)bz * gStride;
    const int br = blockIdx.y, bc = blockIdx.x;

    __shared__ __align__(16) f16 smem[2 * 128 * 64];   // 32 KB -> 5 blocks/CU
    f16* As = smem;
    f16* Bs = smem + 8192;
    f32x4 acc[4][4];
    gemm128_core(Wq, G, br, bc, As, Bs, acc);

    const int lane = threadIdx.x & 63;
    const int wave = threadIdx.x >> 6;
    const int wr = (wave >> 1) * 64;
    const int l15 = lane & 15, quad = lane >> 4;
    const float scale = 0.0625f;              // (2048/8)^-0.5

    #pragma unroll
    for (int i = 0; i < 4; ++i) {
        #pragma unroll
        for (int r = 0; r < 4; ++r) {
            float v = acc[i][0][r];
            v = fmaxf(v, acc[i][1][r]);
            v = fmaxf(v, acc[i][2][r]);
            v = fmaxf(v, acc[i][3][r]);
            #pragma unroll
            for (int m = 1; m <= 8; m <<= 1)
                v = fmaxf(v, __shfl_xor(v, m, 64));
            if (l15 == 0) {
                int row = br * 128 + wr + i * 16 + quad * 4 + r;
                atomicMax(&mkey[(size_t)bi * DIM + row], fkey(scale * v));
            }
        }
    }
}

// ---- out[b,i,j] = (vsum[b,i]/2048) * m[b,j] ----
__global__ __launch_bounds__(256) void k_final(const float* __restrict__ vsum,
                                               const unsigned* __restrict__ mkey,
                                               float* __restrict__ out) {
    int gid = blockIdx.x * 256 + threadIdx.x;     // 8*2048*512 total f32x4
    int b   = gid >> 20;
    int rem = gid & 1048575;
    int i   = rem >> 9;
    int jq  = rem & 511;
    float v = vsum[(b << 11) + i] * (1.f / 2048.f);
    u32x4 k = ((const u32x4*)mkey)[(b << 9) + jq];
    f32x4 o;
    o.x = v * fdecode(k.x);
    o.y = v * fdecode(k.y);
    o.z = v * fdecode(k.z);
    o.w = v * fdecode(k.w);
    ((f32x4*)out)[gid] = o;
}

extern "C" void kernel_launch(void* const* d_in, const int* in_sizes, int n_in,
                              void* d_out, int out_size, void* d_ws, size_t ws_size,
                              hipStream_t stream) {
    const float* x  = (const float*)d_in[0];
    const float* Wq = (const float*)d_in[1];
    float* out = (float*)d_out;
    char* ws = (char*)d_ws;

    const size_t elems = (size_t)DIM * DIM;       // 4,194,304
    unsigned* mkey = (unsigned*)ws;                         // 64 KB
    float*    vsum = (float*)(ws + 65536);                  // 64 KB
    f16*      Wqf  = (f16*)(ws + 131072);                   // 8 MB
    f16*      Xf   = (f16*)(ws + 131072 + elems * 2);

    const size_t need1 = 131072 + elems * 2 * (1 + NB + NB);  // ~142.7 MB
    const size_t need2 = 131072 + elems * 2 * (1 + NB + 1);   // ~84.0 MB

    hipMemsetAsync(ws, 0, 131072, stream);
    k_convert<<<4096, 256, 0, stream>>>(Wq, Wqf, (int)(elems / 4));

    if (ws_size >= need1) {
        f16* G = Xf + NB * elems;
        k_prep<<<dim3(2, 32, NB), 256, 0, stream>>>(x, Xf, vsum);
        k_gram<<<dim3(136, NB), 256, 0, stream>>>(Xf, G, elems, elems);
        k_attn<<<dim3(16, 16, NB), 256, 0, stream>>>(Wqf, G, mkey, elems, 0);
    } else if (ws_size >= need2) {
        f16* G = Xf + NB * elems;
        k_prep<<<dim3(2, 32, NB), 256, 0, stream>>>(x, Xf, vsum);
        for (int b = 0; b < NB; ++b) {
            k_gram<<<dim3(136, 1), 256, 0, stream>>>(Xf + (size_t)b * elems, G, 0, 0);
            k_attn<<<dim3(16, 16, 1), 256, 0, stream>>>(Wqf, G, mkey, 0, b);
        }
    } else {
        f16* G = Xf + elems;
        k_colsum<<<dim3(8, 8, 8), 256, 0, stream>>>(x, vsum);
        for (int b = 0; b < NB; ++b) {
            k_convert<<<4096, 256, 0, stream>>>(x + (size_t)b * elems, Xf, (int)(elems / 4));
            k_gram<<<dim3(136, 1), 256, 0, stream>>>(Xf, G, 0, 0);
            k_attn<<<dim3(16, 16, 1), 256, 0, stream>>>(Wqf, G, mkey, 0, b);
        }
    }
    k_final<<<32768, 256, 0, stream>>>(vsum, mkey, out);
}